// Round 7
// baseline (9327.366 us; speedup 1.0000x reference)
//
#include <hip/hip_runtime.h>

#define LSEQ 50
#define BATCH 256
#define DIN 256
#define LAT 512
#define HID 1024
#define ROWSTRIDE 257  // D_IN + 1 (dt channel)
#define NBLK 256

typedef __attribute__((ext_vector_type(8))) short s16x8;
typedef __attribute__((ext_vector_type(8))) unsigned short u16x8;
typedef __attribute__((ext_vector_type(4))) float f32x4;
using u16 = unsigned short;
using u32 = unsigned int;
using u64 = unsigned long long;

__device__ __forceinline__ u16 bfhi(float v) {
  union { float f; unsigned u; } a; a.f = v;
  return (u16)((a.u + 0x7FFFu + ((a.u >> 16) & 1u)) >> 16);
}
__device__ __forceinline__ void split2(float v, u16& h, u16& l) {
  u16 hu = bfhi(v);
  union { unsigned u; float f; } hf; hf.u = ((unsigned)hu) << 16;
  h = hu; l = bfhi(v - hf.f);
}
__device__ __forceinline__ u32 pks(float v) {
  u16 h, l; split2(v, h, l);
  return ((u32)h << 16) | (u32)l;
}
__device__ __forceinline__ float p2f32(u32 w) {
  union { u32 u; float f; } A, B;
  A.u = w & 0xFFFF0000u; B.u = w << 16;
  return A.f + B.f;
}
__device__ __forceinline__ float sigmoidf_(float x) { return 1.f / (1.f + __expf(-x)); }
__device__ __forceinline__ f32x4 mfma16(s16x8 a, s16x8 b, f32x4 c) {
  return __builtin_amdgcn_mfma_f32_16x16x32_bf16(a, b, c, 0, 0, 0);
}
// agent-scope relaxed atomics: coherent across XCDs, no fence needed
__device__ __forceinline__ u64 ald64(const u32* p) {
  return __hip_atomic_load((const u64*)p, __ATOMIC_RELAXED, __HIP_MEMORY_SCOPE_AGENT);
}
__device__ __forceinline__ u32 ald32(const u32* p) {
  return __hip_atomic_load(p, __ATOMIC_RELAXED, __HIP_MEMORY_SCOPE_AGENT);
}
__device__ __forceinline__ void ast32(u32* p, u32 v) {
  __hip_atomic_store(p, v, __ATOMIC_RELAXED, __HIP_MEMORY_SCOPE_AGENT);
}
// 4 u64 of packed (hi<<16|lo) words (8 elems) -> bf16 hi/lo fragments
__device__ __forceinline__ void unp4(const u64* q, s16x8& h8, s16x8& l8) {
  #pragma unroll
  for (int j = 0; j < 4; ++j) {
    u32 w0 = (u32)q[j], w1 = (u32)(q[j] >> 32);
    h8[2 * j]     = (short)(w0 >> 16);
    h8[2 * j + 1] = (short)(w1 >> 16);
    l8[2 * j]     = (short)(w0 & 0xFFFFu);
    l8[2 * j + 1] = (short)(w1 & 0xFFFFu);
  }
}

// ---------- preprocessing ----------
__global__ __launch_bounds__(256) void tsplit_k(const float* __restrict__ W,
    u16* __restrict__ Thi, u16* __restrict__ Tlo, int K, int N)
{
  __shared__ unsigned Ts[32][33];
  const int bk = blockIdx.x * 32, bn = blockIdx.y * 32;
  const int t = threadIdx.x;
  const int n_l = t & 31, k_l4 = (t >> 5) * 4;
  #pragma unroll
  for (int i = 0; i < 4; i++) {
    float v = W[(size_t)(bk + k_l4 + i) * N + bn + n_l];
    u16 h, l; split2(v, h, l);
    Ts[k_l4 + i][n_l] = ((unsigned)h << 16) | l;
  }
  __syncthreads();
  const int k_l = t & 31, n_l2 = t >> 5;
  #pragma unroll
  for (int i = 0; i < 4; i++) {
    int nn = n_l2 + 8 * i;
    unsigned u = Ts[k_l][nn];
    size_t o = (size_t)(bn + nn) * K + bk + k_l;
    Thi[o] = (u16)(u >> 16);
    Tlo[o] = (u16)(u & 0xFFFFu);
  }
}

__global__ __launch_bounds__(256) void esplit_k(const float* __restrict__ W,
    u16* __restrict__ Phi, u16* __restrict__ Plo)
{
  size_t i4 = ((size_t)blockIdx.x * 256 + threadIdx.x) * 4;
  float4 v = *(const float4*)&W[i4];
  u16 h[4], l[4];
  split2(v.x, h[0], l[0]); split2(v.y, h[1], l[1]);
  split2(v.z, h[2], l[2]); split2(v.w, h[3], l[3]);
  *(ushort4*)&Phi[i4] = make_ushort4(h[0], h[1], h[2], h[3]);
  *(ushort4*)&Plo[i4] = make_ushort4(l[0], l[1], l[2], l[3]);
}

__global__ __launch_bounds__(256) void init_k(u32* __restrict__ c0, u32* __restrict__ bar)
{
  size_t i4 = ((size_t)blockIdx.x * 256 + threadIdx.x) * 4;  // 256 blocks cover 256*1024
  *(uint4*)&c0[i4] = make_uint4(0, 0, 0, 0);
  if (blockIdx.x == 0 && threadIdx.x < 64) bar[threadIdx.x] = 0u;
}

struct MegaArgs {
  const float* data;
  const u16 *w1h, *w1l, *w2h, *w2l;
  const float *b1, *b2;
  const float* whh; const u16 *whhh, *whhl;
  const float* wih; const u16 *wihh, *wihl;
  const float *bih, *bhh;
  u32 *c0, *c1, *h1;   // packed activations (hi<<16|lo)
  u32* bar;
  float* out;
};

template<bool PLANES>
__global__ __launch_bounds__(256, 1) void mega_k(MegaArgs a)
{
  __shared__ u16 POOL[20480];  // 40 KB: carved per phase
  const int tid = threadIdx.x, bid = blockIdx.x;
  const int lane = tid & 63, wave = tid >> 6;
  const int lr = lane & 15, lq = lane >> 4;
  unsigned mygen = 0;
  u32* cnt = a.bar;
  u32* gen = a.bar + 16;  // separate cacheline

  auto gbar = [&]() {
    __syncthreads();  // drains each wave's vmcnt before s_barrier
    if (tid == 0) {
      asm volatile("s_waitcnt vmcnt(0)" ::: "memory");
      unsigned old = __hip_atomic_fetch_add(cnt, 1u, __ATOMIC_RELAXED, __HIP_MEMORY_SCOPE_AGENT);
      if (old == NBLK - 1u) {
        __hip_atomic_store(cnt, 0u, __ATOMIC_RELAXED, __HIP_MEMORY_SCOPE_AGENT);
        asm volatile("s_waitcnt vmcnt(0)" ::: "memory");  // cnt reset visible before release
        __hip_atomic_store(gen, mygen + 1u, __ATOMIC_RELAXED, __HIP_MEMORY_SCOPE_AGENT);
      } else {
        while (__hip_atomic_load(gen, __ATOMIC_RELAXED, __HIP_MEMORY_SCOPE_AGENT) <= mygen)
          __builtin_amdgcn_s_sleep(2);
      }
    }
    mygen++;
    __syncthreads();
    asm volatile("" ::: "memory");
  };

  // MLP B staging map (64 weight-rows x 32 k)
  const int sbr = tid >> 2, sbk = (tid & 3) << 3;
  // GRU staging map (32 rows x 32 k, ushort4)
  const int srow = tid >> 3, skq = (tid & 7) << 2;
  const int sidx = srow * 40 + skq;

  for (int t = 0; t < LSEQ; ++t) {
    u32* chi = (t & 1) ? a.c1 : a.c0;
    u32* nxt = (t & 1) ? a.c0 : a.c1;

    for (int s = 0; s < 3; ++s) {
      // ======== G1: h1 = tanh(y @ w1 + b1);  128 blocks, tile 32x64 ========
      if (bid < 128) {
        u16* Bh = POOL;           // [2][64][40]
        u16* Bl = POOL + 5120;
        const int m0 = (bid >> 4) << 5, n0 = (bid & 15) << 6;
        const int wmr = (wave >> 1) << 4, wn = (wave & 1) << 5;
        const int arow = m0 + wmr + lr;
        const u32* ab = chi + (size_t)arow * HID;  // y = cols 0..511
        u64 q[4][4];
        #pragma unroll
        for (int ps = 0; ps < 4; ++ps) {
          const u32* p = ab + ps * 32 + lq * 8;
          #pragma unroll
          for (int j = 0; j < 4; ++j) q[ps][j] = ald64(p + 2 * j);
        }
        {
          size_t o = (size_t)(n0 + sbr) * 512 + sbk;
          *(u16x8*)&Bh[sbr * 40 + sbk] = *(const u16x8*)&a.w1h[o];
          *(u16x8*)&Bl[sbr * 40 + sbk] = *(const u16x8*)&a.w1l[o];
        }
        f32x4 acc0 = {0,0,0,0}, acc1 = {0,0,0,0};
        __syncthreads();
        #pragma unroll
        for (int it = 0; it < 16; ++it) {
          const int db = it & 1, nb = db ^ 1;
          u16x8 pbh, pbl;
          if (it + 1 < 16) {
            size_t o = (size_t)(n0 + sbr) * 512 + (it + 1) * 32 + sbk;
            pbh = *(const u16x8*)&a.w1h[o];
            pbl = *(const u16x8*)&a.w1l[o];
          }
          s16x8 ah, al; unp4(q[it & 3], ah, al);
          if (it + 4 < 16) {
            const u32* p = ab + (it + 4) * 32 + lq * 8;
            #pragma unroll
            for (int j = 0; j < 4; ++j) q[it & 3][j] = ald64(p + 2 * j);
          }
          const int fb0 = db * 2560 + (wn + lr) * 40 + lq * 8;
          const int fb1 = db * 2560 + (wn + 16 + lr) * 40 + lq * 8;
          s16x8 bh0 = *(const s16x8*)&Bh[fb0], bl0 = *(const s16x8*)&Bl[fb0];
          s16x8 bh1 = *(const s16x8*)&Bh[fb1], bl1 = *(const s16x8*)&Bl[fb1];
          acc0 = mfma16(ah, bh0, acc0); acc0 = mfma16(ah, bl0, acc0); acc0 = mfma16(al, bh0, acc0);
          acc1 = mfma16(ah, bh1, acc1); acc1 = mfma16(ah, bl1, acc1); acc1 = mfma16(al, bh1, acc1);
          if (it + 1 < 16) {
            *(u16x8*)&Bh[nb * 2560 + sbr * 40 + sbk] = pbh;
            *(u16x8*)&Bl[nb * 2560 + sbr * 40 + sbk] = pbl;
          }
          __syncthreads();
        }
        #pragma unroll
        for (int jt = 0; jt < 2; ++jt) {
          f32x4 A = jt ? acc1 : acc0;
          const int col = n0 + wn + jt * 16 + lr;
          const float bv = a.b1[col];
          #pragma unroll
          for (int r = 0; r < 4; ++r) {
            const int row = m0 + wmr + lq * 4 + r;
            ast32(&a.h1[(size_t)row * HID + col], pks(tanhf(A[r] + bv)));
          }
        }
      }
      gbar();
      // ======== G2: y += (h1 @ w2 + b2)*dt/3;  128 blocks, tile 16x64 ========
      if (bid < 128) {
        u16* Bh = POOL;
        u16* Bl = POOL + 5120;
        const int m0 = (bid >> 3) << 4, n0 = (bid & 7) << 6;
        const int wn = wave << 4;
        const int arow = m0 + lr;
        const u32* ab = a.h1 + (size_t)arow * HID;
        u64 q[4][4];
        #pragma unroll
        for (int ps = 0; ps < 4; ++ps) {
          const u32* p = ab + ps * 32 + lq * 8;
          #pragma unroll
          for (int j = 0; j < 4; ++j) q[ps][j] = ald64(p + 2 * j);
        }
        {
          size_t o = (size_t)(n0 + sbr) * 1024 + sbk;
          *(u16x8*)&Bh[sbr * 40 + sbk] = *(const u16x8*)&a.w2h[o];
          *(u16x8*)&Bl[sbr * 40 + sbk] = *(const u16x8*)&a.w2l[o];
        }
        f32x4 acc = {0,0,0,0};
        __syncthreads();
        #pragma unroll
        for (int it = 0; it < 32; ++it) {
          const int db = it & 1, nb = db ^ 1;
          u16x8 pbh, pbl;
          if (it + 1 < 32) {
            size_t o = (size_t)(n0 + sbr) * 1024 + (it + 1) * 32 + sbk;
            pbh = *(const u16x8*)&a.w2h[o];
            pbl = *(const u16x8*)&a.w2l[o];
          }
          s16x8 ah, al; unp4(q[it & 3], ah, al);
          if (it + 4 < 32) {
            const u32* p = ab + (it + 4) * 32 + lq * 8;
            #pragma unroll
            for (int j = 0; j < 4; ++j) q[it & 3][j] = ald64(p + 2 * j);
          }
          const int fb = db * 2560 + (wn + lr) * 40 + lq * 8;
          s16x8 bh = *(const s16x8*)&Bh[fb], bl = *(const s16x8*)&Bl[fb];
          acc = mfma16(ah, bh, acc); acc = mfma16(ah, bl, acc); acc = mfma16(al, bh, acc);
          if (it + 1 < 32) {
            *(u16x8*)&Bh[nb * 2560 + sbr * 40 + sbk] = pbh;
            *(u16x8*)&Bl[nb * 2560 + sbr * 40 + sbk] = pbl;
          }
          __syncthreads();
        }
        const int col = n0 + wn + lr;
        const float bv = a.b2[col];
        #pragma unroll
        for (int r = 0; r < 4; ++r) {
          const int row = m0 + lq * 4 + r;
          float dt3 = a.data[(size_t)(t * BATCH + row) * ROWSTRIDE + DIN] * (1.f / 3.f);
          u32* yp = &chi[(size_t)row * HID + col];
          float y = p2f32(ald32(yp)) + (acc[r] + bv) * dt3;
          ast32(yp, pks(y));
        }
      }
      gbar();
    }

    // ======== GRU: gh(K=1024) + gi(K=256) + pointwise; 256 blocks, tile 32x32x3g ========
    {
      u16* GBh = POOL;             // [2][3][32][40]
      u16* GBl = POOL + 7680;
      u16* GAh = POOL + 15360;     // [2][32][40] (gi A)
      u16* GAl = POOL + 17920;
      const int m0 = (bid >> 5) << 5, g0 = (bid & 31) << 5;
      const int wm = (wave >> 1) << 4, wn = (wave & 1) << 4;
      f32x4 aR = {0,0,0,0}, aZ = {0,0,0,0}, aNh = {0,0,0,0}, aNi = {0,0,0,0};
      const int arow = m0 + wm + lr;
      const u32* ab = chi + (size_t)arow * HID;
      u64 q[4][4];
      #pragma unroll
      for (int ps = 0; ps < 4; ++ps) {
        const u32* p = ab + ps * 32 + lq * 8;
        #pragma unroll
        for (int j = 0; j < 4; ++j) q[ps][j] = ald64(p + 2 * j);
      }
      #pragma unroll
      for (int g = 0; g < 3; ++g) {
        const size_t rrow = (size_t)(g * 1024 + g0 + srow);
        if (PLANES) {
          size_t o = rrow * 1024 + skq;
          *(ushort4*)&GBh[g * 1280 + sidx] = *(const ushort4*)&a.whhh[o];
          *(ushort4*)&GBl[g * 1280 + sidx] = *(const ushort4*)&a.whhl[o];
        } else {
          float4 w4 = *(const float4*)&a.whh[rrow * 1024 + skq];
          u16 h0,l0,h1,l1,h2,l2,h3,l3;
          split2(w4.x,h0,l0); split2(w4.y,h1,l1); split2(w4.z,h2,l2); split2(w4.w,h3,l3);
          *(ushort4*)&GBh[g * 1280 + sidx] = make_ushort4(h0,h1,h2,h3);
          *(ushort4*)&GBl[g * 1280 + sidx] = make_ushort4(l0,l1,l2,l3);
        }
      }
      __syncthreads();
      #pragma unroll
      for (int it = 0; it < 32; ++it) {
        const int db = it & 1, nb = db ^ 1;
        ushort4 p0h,p0l,p1h,p1l,p2h,p2l;
        if (it + 1 < 32) {
          const int k0 = (it + 1) << 5;
          if (PLANES) {
            size_t r0 = (size_t)(0 * 1024 + g0 + srow) * 1024 + k0 + skq;
            size_t r1 = (size_t)(1 * 1024 + g0 + srow) * 1024 + k0 + skq;
            size_t r2 = (size_t)(2 * 1024 + g0 + srow) * 1024 + k0 + skq;
            p0h = *(const ushort4*)&a.whhh[r0]; p0l = *(const ushort4*)&a.whhl[r0];
            p1h = *(const ushort4*)&a.whhh[r1]; p1l = *(const ushort4*)&a.whhl[r1];
            p2h = *(const ushort4*)&a.whhh[r2]; p2l = *(const ushort4*)&a.whhl[r2];
          } else {
            #pragma unroll
            for (int g = 0; g < 3; ++g) {
              float4 w4 = *(const float4*)&a.whh[(size_t)(g * 1024 + g0 + srow) * 1024 + k0 + skq];
              u16 h0,l0,h1,l1,h2,l2,h3,l3;
              split2(w4.x,h0,l0); split2(w4.y,h1,l1); split2(w4.z,h2,l2); split2(w4.w,h3,l3);
              ushort4 hh = make_ushort4(h0,h1,h2,h3), ll = make_ushort4(l0,l1,l2,l3);
              if (g == 0) { p0h = hh; p0l = ll; }
              else if (g == 1) { p1h = hh; p1l = ll; }
              else { p2h = hh; p2l = ll; }
            }
          }
        }
        s16x8 ah, al; unp4(q[it & 3], ah, al);
        if (it + 4 < 32) {
          const u32* p = ab + (it + 4) * 32 + lq * 8;
          #pragma unroll
          for (int j = 0; j < 4; ++j) q[it & 3][j] = ald64(p + 2 * j);
        }
        #pragma unroll
        for (int g = 0; g < 3; ++g) {
          const int fb = db * 3840 + g * 1280 + (wn + lr) * 40 + lq * 8;
          s16x8 bh = *(const s16x8*)&GBh[fb], bl = *(const s16x8*)&GBl[fb];
          f32x4 c = (g == 0) ? aR : (g == 1) ? aZ : aNh;
          c = mfma16(ah, bh, c); c = mfma16(ah, bl, c); c = mfma16(al, bh, c);
          if (g == 0) aR = c; else if (g == 1) aZ = c; else aNh = c;
        }
        if (it + 1 < 32) {
          *(ushort4*)&GBh[nb * 3840 + 0 * 1280 + sidx] = p0h; *(ushort4*)&GBl[nb * 3840 + 0 * 1280 + sidx] = p0l;
          *(ushort4*)&GBh[nb * 3840 + 1 * 1280 + sidx] = p1h; *(ushort4*)&GBl[nb * 3840 + 1 * 1280 + sidx] = p1l;
          *(ushort4*)&GBh[nb * 3840 + 2 * 1280 + sidx] = p2h; *(ushort4*)&GBl[nb * 3840 + 2 * 1280 + sidx] = p2l;
        }
        __syncthreads();
      }
      // gi phase: A = x_t (read-only input, normal loads, split inline)
      {
        const float* xp = &a.data[(size_t)(t * BATCH + m0 + srow) * ROWSTRIDE + skq];
        u16 xh[4], xl[4];
        #pragma unroll
        for (int i = 0; i < 4; i++) split2(xp[i], xh[i], xl[i]);
        *(ushort4*)&GAh[sidx] = make_ushort4(xh[0], xh[1], xh[2], xh[3]);
        *(ushort4*)&GAl[sidx] = make_ushort4(xl[0], xl[1], xl[2], xl[3]);
        #pragma unroll
        for (int g = 0; g < 3; ++g) {
          const size_t rrow = (size_t)(g * 1024 + g0 + srow);
          if (PLANES) {
            size_t o = rrow * 256 + skq;
            *(ushort4*)&GBh[g * 1280 + sidx] = *(const ushort4*)&a.wihh[o];
            *(ushort4*)&GBl[g * 1280 + sidx] = *(const ushort4*)&a.wihl[o];
          } else {
            float4 w4 = *(const float4*)&a.wih[rrow * 256 + skq];
            u16 h0,l0,h1,l1,h2,l2,h3,l3;
            split2(w4.x,h0,l0); split2(w4.y,h1,l1); split2(w4.z,h2,l2); split2(w4.w,h3,l3);
            *(ushort4*)&GBh[g * 1280 + sidx] = make_ushort4(h0,h1,h2,h3);
            *(ushort4*)&GBl[g * 1280 + sidx] = make_ushort4(l0,l1,l2,l3);
          }
        }
      }
      __syncthreads();
      #pragma unroll
      for (int it = 0; it < 8; ++it) {
        const int db = it & 1, nb = db ^ 1;
        ushort4 nah, nal, p0h,p0l,p1h,p1l,p2h,p2l;
        if (it + 1 < 8) {
          const int k0 = (it + 1) << 5;
          const float* xp = &a.data[(size_t)(t * BATCH + m0 + srow) * ROWSTRIDE + k0 + skq];
          u16 xh[4], xl[4];
          #pragma unroll
          for (int i = 0; i < 4; i++) split2(xp[i], xh[i], xl[i]);
          nah = make_ushort4(xh[0], xh[1], xh[2], xh[3]);
          nal = make_ushort4(xl[0], xl[1], xl[2], xl[3]);
          if (PLANES) {
            size_t r0 = (size_t)(0 * 1024 + g0 + srow) * 256 + k0 + skq;
            size_t r1 = (size_t)(1 * 1024 + g0 + srow) * 256 + k0 + skq;
            size_t r2 = (size_t)(2 * 1024 + g0 + srow) * 256 + k0 + skq;
            p0h = *(const ushort4*)&a.wihh[r0]; p0l = *(const ushort4*)&a.wihl[r0];
            p1h = *(const ushort4*)&a.wihh[r1]; p1l = *(const ushort4*)&a.wihl[r1];
            p2h = *(const ushort4*)&a.wihh[r2]; p2l = *(const ushort4*)&a.wihl[r2];
          } else {
            #pragma unroll
            for (int g = 0; g < 3; ++g) {
              float4 w4 = *(const float4*)&a.wih[(size_t)(g * 1024 + g0 + srow) * 256 + k0 + skq];
              u16 h0,l0,h1,l1,h2,l2,h3,l3;
              split2(w4.x,h0,l0); split2(w4.y,h1,l1); split2(w4.z,h2,l2); split2(w4.w,h3,l3);
              ushort4 hh = make_ushort4(h0,h1,h2,h3), ll = make_ushort4(l0,l1,l2,l3);
              if (g == 0) { p0h = hh; p0l = ll; }
              else if (g == 1) { p1h = hh; p1l = ll; }
              else { p2h = hh; p2l = ll; }
            }
          }
        }
        const int fa = db * 1280 + (wm + lr) * 40 + lq * 8;
        s16x8 ah = *(const s16x8*)&GAh[fa];
        s16x8 al = *(const s16x8*)&GAl[fa];
        #pragma unroll
        for (int g = 0; g < 3; ++g) {
          const int fb = db * 3840 + g * 1280 + (wn + lr) * 40 + lq * 8;
          s16x8 bh = *(const s16x8*)&GBh[fb], bl = *(const s16x8*)&GBl[fb];
          f32x4 c = (g == 0) ? aR : (g == 1) ? aZ : aNi;
          c = mfma16(ah, bh, c); c = mfma16(ah, bl, c); c = mfma16(al, bh, c);
          if (g == 0) aR = c; else if (g == 1) aZ = c; else aNi = c;
        }
        if (it + 1 < 8) {
          *(ushort4*)&GAh[nb * 1280 + sidx] = nah; *(ushort4*)&GAl[nb * 1280 + sidx] = nal;
          *(ushort4*)&GBh[nb * 3840 + 0 * 1280 + sidx] = p0h; *(ushort4*)&GBl[nb * 3840 + 0 * 1280 + sidx] = p0l;
          *(ushort4*)&GBh[nb * 3840 + 1 * 1280 + sidx] = p1h; *(ushort4*)&GBl[nb * 3840 + 1 * 1280 + sidx] = p1l;
          *(ushort4*)&GBh[nb * 3840 + 2 * 1280 + sidx] = p2h; *(ushort4*)&GBl[nb * 3840 + 2 * 1280 + sidx] = p2l;
        }
        __syncthreads();
      }
      // epilogue
      #pragma unroll
      for (int r4 = 0; r4 < 4; ++r4) {
        const int row = m0 + wm + lq * 4 + r4;
        const int jg = g0 + wn + lr;
        float rr = sigmoidf_(aR[r4] + a.bih[jg] + a.bhh[jg]);
        float zz = sigmoidf_(aZ[r4] + a.bih[1024 + jg] + a.bhh[1024 + jg]);
        float nn = tanhf(aNi[r4] + a.bih[2048 + jg] + rr * (aNh[r4] + a.bhh[2048 + jg]));
        float hv = p2f32(ald32(&chi[(size_t)row * HID + jg]));
        float val = (1.f - zz) * nn + zz * hv;
        a.out[(size_t)LSEQ * BATCH * LAT + (size_t)row * HID + jg] = val;  // output 1
        if (jg < LAT) {
          a.out[((size_t)t * BATCH + row) * LAT + jg] = val;              // output 0
          u32 pv = pks(val);
          ast32(&nxt[(size_t)row * HID + jg], pv);
          ast32(&nxt[(size_t)row * HID + jg + LAT], pv);
        }
      }
    }
    gbar();
  }
}

extern "C" void kernel_launch(void* const* d_in, const int* in_sizes, int n_in,
                              void* d_out, int out_size, void* d_ws, size_t ws_size,
                              hipStream_t stream)
{
  const float* data = (const float*)d_in[0];
  const float* w1   = (const float*)d_in[1];
  const float* b1   = (const float*)d_in[2];
  const float* w2   = (const float*)d_in[3];
  const float* b2   = (const float*)d_in[4];
  const float* wih  = (const float*)d_in[5];
  const float* bih  = (const float*)d_in[6];
  const float* whh  = (const float*)d_in[7];
  const float* bhh  = (const float*)d_in[8];
  float* out = (float*)d_out;

  char* w = (char*)d_ws;
  auto alloc = [&](size_t bytes) { char* p = w; w += (bytes + 255) & ~(size_t)255; return p; };
  u16* w1h = (u16*)alloc((size_t)512 * 1024 * 2);   // [1024 n][512 k]
  u16* w1l = (u16*)alloc((size_t)512 * 1024 * 2);
  u16* w2h = (u16*)alloc((size_t)512 * 1024 * 2);   // [512 n][1024 k]
  u16* w2l = (u16*)alloc((size_t)512 * 1024 * 2);
  u32* c0  = (u32*)alloc((size_t)BATCH * HID * 4);  // packed hcat ping
  u32* c1  = (u32*)alloc((size_t)BATCH * HID * 4);  // pong
  u32* h1  = (u32*)alloc((size_t)BATCH * HID * 4);  // packed h1
  u32* bar = (u32*)alloc(256);
  size_t base = (size_t)(w - (char*)d_ws);
  size_t need_opt = base + 2 * ((size_t)3072 * 1024 * 2) + 2 * ((size_t)3072 * 256 * 2) + 4096;
  bool planes = ws_size >= need_opt;
  u16 *whhh = nullptr, *whhl = nullptr, *wihh = nullptr, *wihl = nullptr;
  if (planes) {
    whhh = (u16*)alloc((size_t)3072 * 1024 * 2);
    whhl = (u16*)alloc((size_t)3072 * 1024 * 2);
    wihh = (u16*)alloc((size_t)3072 * 256 * 2);
    wihl = (u16*)alloc((size_t)3072 * 256 * 2);
  }

  tsplit_k<<<dim3(512 / 32, 1024 / 32), 256, 0, stream>>>(w1, w1h, w1l, 512, 1024);
  tsplit_k<<<dim3(1024 / 32, 512 / 32), 256, 0, stream>>>(w2, w2h, w2l, 1024, 512);
  if (planes) {
    esplit_k<<<dim3((3072 * 1024) / 1024), 256, 0, stream>>>(whh, whhh, whhl);
    esplit_k<<<dim3((3072 * 256) / 1024), 256, 0, stream>>>(wih, wihh, wihl);
  }
  init_k<<<dim3(256), 256, 0, stream>>>(c0, bar);

  MegaArgs ma;
  ma.data = data;
  ma.w1h = w1h; ma.w1l = w1l; ma.w2h = w2h; ma.w2l = w2l;
  ma.b1 = b1; ma.b2 = b2;
  ma.whh = whh; ma.whhh = whhh; ma.whhl = whhl;
  ma.wih = wih; ma.wihh = wihh; ma.wihl = wihl;
  ma.bih = bih; ma.bhh = bhh;
  ma.c0 = c0; ma.c1 = c1; ma.h1 = h1;
  ma.bar = bar; ma.out = out;
  void* kargs[] = { &ma };
  hipLaunchCooperativeKernel(
      planes ? reinterpret_cast<void*>(mega_k<true>) : reinterpret_cast<void*>(mega_k<false>),
      dim3(NBLK), dim3(256), kargs, 0, stream);
}